// Round 14
// baseline (199.236 us; speedup 1.0000x reference)
//
#include <hip/hip_runtime.h>
#include <hip/hip_bf16.h>
#include <cstddef>

// Problem dims
#define BB 8
#define LL 2048
#define EE 512
#define KCONV 1536   // 3*E
#define LPAD 2050    // L + 2 pad rows

typedef _Float16 h16;
typedef _Float16 h16x2 __attribute__((ext_vector_type(2)));
typedef _Float16 h16x4 __attribute__((ext_vector_type(4)));
typedef _Float16 h16x8 __attribute__((ext_vector_type(8)));
typedef float    f32x4 __attribute__((ext_vector_type(4)));

// ---------------- workspace layout (bytes) ----------------
static const size_t OFF_WT1  = 0;         // [512][1536] h16
static const size_t OFF_WT2  = 1572864;   // [512][1536] h16
static const size_t OFF_WPB  = 3145728;   // [512][512]  h16
static const size_t OFF_CNT2 = 3670016;   // int[4096] per-block counts
static const size_t OFF_H0P  = 4194304;   // [8][2050][512] h16
static const size_t OFF_H1P  = 20987904;  // [8][2050][512] h16
static const size_t OFF_H2T  = 37781504;  // [8][512][2048] h16 (conv2 out, transposed)
static const size_t OFF_XF   = 4194304;   // [8][512][1024] h16x2 half-spectrum (reuses h0p, dead)
static const size_t OFF_H3E  = 54558720;  // [8][512][2048] h16
static const size_t OFF_H3T  = 20987904;  // [8][2048][512] h16 (reuses h1p, dead after conv2)
static const size_t WS_NEED  = 71335936;

__device__ __forceinline__ int padi(int i) { return i + (i >> 5); }
// base-4 digit reversal of a 10-bit index (involution)
__device__ __forceinline__ int dr5(int n) {
    return ((n & 3) << 8) | (((n >> 2) & 3) << 6) | (((n >> 4) & 3) << 4)
         | (((n >> 6) & 3) << 2) | ((n >> 8) & 3);
}
#define TWOPI_2048 0.0030679616f   // 2*pi/2048

// ---------------- prep+embed merged: blocks 0..447 weight transpose, rest embed ----------------
__global__ __launch_bounds__(256) void prep_embed_kernel(
    const float* __restrict__ Wc1, const float* __restrict__ Wc2,
    const float* __restrict__ Wp,
    h16* __restrict__ Wt1, h16* __restrict__ Wt2, h16* __restrict__ Wpb,
    const int* __restrict__ x, const float* __restrict__ Wtok,
    const float* __restrict__ Wpos, h16* __restrict__ h0p, h16* __restrict__ h1p)
{
    int blk = blockIdx.x, t = threadIdx.x;
    __shared__ float tl[64][65];
    if (blk < 384) {
        const float* src = (blk < 192) ? Wc1 : Wc2;
        h16* dst = (blk < 192) ? Wt1 : Wt2;
        int tile = blk % 192;                 // 8 o-tiles x 24 r-tiles
        int o0 = (tile / 24) * 64, r0 = (tile % 24) * 64;
        #pragma unroll
        for (int it = 0; it < 4; ++it) {
            int idx = it * 256 + t;           // 1024 x float4
            int rr = idx >> 4, oo4 = (idx & 15) * 4;
            f32x4 v = *(const f32x4*)(src + (size_t)(r0 + rr) * 512 + o0 + oo4);
            tl[rr][oo4] = v[0]; tl[rr][oo4 + 1] = v[1];
            tl[rr][oo4 + 2] = v[2]; tl[rr][oo4 + 3] = v[3];
        }
        __syncthreads();
        #pragma unroll
        for (int it = 0; it < 4; ++it) {
            int idx = it * 256 + t;           // 1024 x h16x4
            int oo = idx & 63, rr4 = (idx >> 6) * 4;
            h16x4 v;
            v.x = (h16)tl[rr4][oo]; v.y = (h16)tl[rr4 + 1][oo];
            v.z = (h16)tl[rr4 + 2][oo]; v.w = (h16)tl[rr4 + 3][oo];
            *(h16x4*)(dst + (size_t)(o0 + oo) * 1536 + r0 + rr4) = v;
        }
    } else if (blk < 448) {
        int base = (blk - 384) * 4096;
        #pragma unroll
        for (int i = 0; i < 4; ++i) {
            int idx = base + (i * 256 + t) * 4;
            f32x4 a = *(const f32x4*)(Wp + idx);
            h16x4 v; v.x = (h16)a[0]; v.y = (h16)a[1]; v.z = (h16)a[2]; v.w = (h16)a[3];
            *(h16x4*)(Wpb + idx) = v;         // Wp already [out][in] = Bt[n][k]
        }
    } else {
        int rowg = (blk - 448) * 4 + (t >> 6);   // 0..16399
        int b = rowg / LPAD, r = rowg % LPAD;
        int lane = t & 63;
        size_t o = (size_t)rowg * 512 + lane * 8;
        if (r == 0 || r == LPAD - 1) {
            h16x8 z;
            #pragma unroll
            for (int j = 0; j < 8; ++j) z[j] = (h16)0.f;
            *(h16x8*)(h0p + o) = z;
            *(h16x8*)(h1p + o) = z;           // zero conv1-output pads too
        } else {
            int l = r - 1;
            int tok = x[b * LL + l];
            const f32x4* wt = (const f32x4*)(Wtok + (size_t)tok * 512 + lane * 8);
            const f32x4* wp = (const f32x4*)(Wpos + (size_t)l * 512 + lane * 8);
            f32x4 a0 = wt[0], a1 = wt[1], p0 = wp[0], p1 = wp[1];
            h16x8 v;
            #pragma unroll
            for (int j = 0; j < 4; ++j) v[j] = (h16)(a0[j] + p0[j]);
            #pragma unroll
            for (int j = 0; j < 4; ++j) v[4 + j] = (h16)(a1[j] + p1[j]);
            *(h16x8*)(h0p + o) = v;
        }
    }
}

// ---------------- GEMM: A direct-from-L2, B LDS depth-3, compiler-managed waits ----------
// BM=256 BN=128 BK=64, 8 waves. Per iter program order: STAGE B(kt+2) ->
// ALOAD A(kt+1) (alternate named frag buffers) -> MFMAs consuming A(kt).
// Compiler's dependency wait for A(kt) (oldest) drains the older B(kt+1)
// before this iter's barrier; B(kt+2)/A(kt+1) stay in flight (T4 pipeline,
// zero manual steady-state vmcnt). LDS = 3 B-buffers only (48KB). T2 swizzle
// on B (linear LDS dest + inverse-swizzled global source + swizzled ds_read).
template<int KTOT, bool RELU, bool TRANSOUT, typename OT>
__global__ __launch_bounds__(512) void gemm3_kernel(
    const h16* __restrict__ A, int a_extra,
    const h16* __restrict__ Bt, const float* __restrict__ bias,
    OT* __restrict__ out, int out_extra, int out_off,
    float* __restrict__ tail)
{
    extern __shared__ __align__(16) h16 lds[];   // 3x(128x64) B
    const int NKT = KTOT / 64;

    int t = threadIdx.x;                      // 0..511
    int w = t >> 6, ln = t & 63;
    int mt = blockIdx.x, nt = blockIdx.y;     // mt 0..63, nt 0..3
    int b = mt >> 3;                          // 8 256-row tiles per batch
    const h16* Ab = A + (size_t)mt * (256 * 512) + (size_t)b * a_extra;
    const h16* Bb = Bt + (size_t)nt * 128 * KTOT;

    int srow = t >> 3;                        // 0..63 staging row
    int scol = (t & 7) * 8;                   // staging col (h16)
    int wr = (w >> 1) * 64, wc = (w & 1) * 64;
    int fr = ln & 15, fg = (ln >> 4) * 8;

    f32x4 acc[4][4];
    #pragma unroll
    for (int m = 0; m < 4; ++m)
        #pragma unroll
        for (int n = 0; n < 4; ++n) acc[m][n] = {0.f, 0.f, 0.f, 0.f};

    // B staging: 2 global_load_lds per wave per K-tile
#define STAGE3(KT, BUF)                                                          \
    {                                                                            \
        int k0_ = (KT) * 64;                                                     \
        h16* sb_ = lds + (BUF) * 8192;                                           \
        _Pragma("unroll")                                                        \
        for (int q = 0; q < 2; ++q) {                                            \
            int row_ = q * 64 + srow;                                            \
            int sc_ = scol ^ ((row_ & 7) << 3);                                  \
            __builtin_amdgcn_global_load_lds(                                    \
                (const __attribute__((address_space(1))) unsigned int*)(Bb + (size_t)row_ * KTOT + k0_ + sc_), \
                (__attribute__((address_space(3))) unsigned int*)(sb_ + row_ * 64 + scol), \
                16, 0, 0);                                                       \
        }                                                                        \
    }

    // A fragments direct from global (L2-hot panel slice); af[kk-half][m]
#define ALOAD(KT, AF)                                                            \
    {                                                                            \
        int k0_ = (KT) * 64;                                                     \
        _Pragma("unroll")                                                        \
        for (int kk2 = 0; kk2 < 2; ++kk2)                                        \
            _Pragma("unroll")                                                    \
            for (int m = 0; m < 4; ++m)                                          \
                AF[kk2][m] = *(const h16x8*)(Ab + (size_t)(wr + m * 16 + fr) * 512 + k0_ + kk2 * 32 + fg); \
    }

    // one K-tile of MFMAs from Bs[buf] + af
#define MFMA_TILE(BUF, AF)                                                       \
    {                                                                            \
        const h16* sb = lds + (BUF) * 8192;                                      \
        _Pragma("unroll")                                                        \
        for (int kk2 = 0; kk2 < 2; ++kk2) {                                      \
            h16x8 bf[4];                                                         \
            _Pragma("unroll")                                                    \
            for (int n = 0; n < 4; ++n) {                                        \
                int brow = wc + n * 16 + fr;                                     \
                bf[n] = *(const h16x8*)(sb + brow * 64 + ((kk2 * 32 + fg) ^ ((brow & 7) << 3))); \
            }                                                                    \
            __builtin_amdgcn_s_setprio(1);                                       \
            _Pragma("unroll")                                                    \
            for (int m = 0; m < 4; ++m)                                          \
                _Pragma("unroll")                                                \
                for (int n = 0; n < 4; ++n)                                      \
                    acc[m][n] = __builtin_amdgcn_mfma_f32_16x16x32_f16(AF[kk2][m], bf[n], acc[m][n], 0, 0, 0); \
            __builtin_amdgcn_s_setprio(0);                                       \
        }                                                                        \
    }

    h16x8 afA[2][4], afB[2][4];

    // prologue: B(0),B(1) staged; A(0) loaded; drain B(0) (oldest 2 of 12)
    STAGE3(0, 0);
    STAGE3(1, 1);
    __builtin_amdgcn_sched_barrier(0);
    ALOAD(0, afA);
    __builtin_amdgcn_sched_barrier(0);
    asm volatile("s_waitcnt vmcnt(10)" ::: "memory");   // B(0) resident
    __builtin_amdgcn_s_barrier();
    __builtin_amdgcn_sched_barrier(0);

    for (int kt = 0; kt < NKT; kt += 2) {
        // even iter: consume afA (tile kt), load afB (tile kt+1)
        if (kt + 2 < NKT) STAGE3(kt + 2, (kt + 2) % 3);
        if (kt + 1 < NKT) ALOAD(kt + 1, afB);
        MFMA_TILE(kt % 3, afA);
        __builtin_amdgcn_sched_barrier(0);
        __builtin_amdgcn_s_barrier();
        __builtin_amdgcn_sched_barrier(0);
        // odd iter: consume afB (tile kt+1), load afA (tile kt+2)
        if (kt + 3 < NKT) STAGE3(kt + 3, (kt + 3) % 3);
        if (kt + 2 < NKT) ALOAD(kt + 2, afA);
        MFMA_TILE((kt + 1) % 3, afB);
        if (kt + 2 < NKT) {
            __builtin_amdgcn_sched_barrier(0);
            __builtin_amdgcn_s_barrier();
            __builtin_amdgcn_sched_barrier(0);
        }
    }
#undef STAGE3
#undef ALOAD
#undef MFMA_TILE

    int fq = (ln >> 4) * 4;
    if constexpr (TRANSOUT) {
        int mtl = (mt & 7) * 256;
        #pragma unroll
        for (int n = 0; n < 4; ++n) {
            int col = nt * 128 + wc + n * 16 + fr;
            float bv = bias[col];
            #pragma unroll
            for (int m = 0; m < 4; ++m) {
                h16x4 hv;
                #pragma unroll
                for (int r = 0; r < 4; ++r) {
                    float xv = acc[m][n][r] + bv;
                    if (RELU) xv = fmaxf(xv, 0.f);
                    hv[r] = (h16)xv;
                }
                int l0a = mtl + wr + m * 16 + fq;
                *(h16x4*)((h16*)out + ((size_t)(b * 512 + col)) * 2048 + l0a) = hv;
            }
        }
    } else {
        #pragma unroll
        for (int n = 0; n < 4; ++n) {
            int col = nt * 128 + wc + n * 16 + fr;
            float bv = bias[col];
            #pragma unroll
            for (int m = 0; m < 4; ++m) {
                #pragma unroll
                for (int r = 0; r < 4; ++r) {
                    int grow = wr + m * 16 + fq + r;
                    float v = acc[m][n][r] + bv;
                    if (RELU) v = fmaxf(v, 0.f);
                    size_t oi = (size_t)(mt * 256 + grow) * 512 + (size_t)b * out_extra + out_off + col;
                    out[oi] = (OT)v;
                }
            }
        }
    }
    if (tail && mt == 0 && nt == 0 && t == 0) tail[0] = 0.f;
}

// ---------------- forward: real 2048-FFT via 1024-pt radix-4 DIT + untangle ----------------
__global__ __launch_bounds__(256) void fft_fwd_kernel(
    const h16* __restrict__ h2t, h16x2* __restrict__ Xf, int* __restrict__ cnt2)
{
    __shared__ float sre[1056], sim[1056];
    __shared__ float red[4]; __shared__ int redc[4];
    int t = threadIdx.x;
    int b = blockIdx.x >> 9, e = blockIdx.x & 511;
    const h16* src = h2t + ((size_t)b * 512 + e) * 2048;
    #pragma unroll
    for (int j = 0; j < 2; ++j) {
        int n0 = j * 512 + t * 2;
        h16x4 v = *(const h16x4*)(src + n0 * 2);
        int d0 = padi(dr5(n0)), d1 = padi(dr5(n0 + 1));
        sre[d0] = (float)v.x; sim[d0] = (float)v.y;
        sre[d1] = (float)v.z; sim[d1] = (float)v.w;
    }
    __syncthreads();
    #pragma unroll
    for (int s = 0; s < 5; ++s) {
        int L = 1 << (2 * s);
        int K = 512 >> (2 * s);
        int p = t & (L - 1);
        int base = (t >> (2 * s)) * 4 * L + p;   // one butterfly per thread
        float th = (float)(p * K) * TWOPI_2048;
        float s1, c1;
        __sincosf(th, &s1, &c1);
        float c2 = 1.f - 2.f * s1 * s1, s2 = 2.f * s1 * c1;      // double angle
        float c3 = c1 * c2 - s1 * s2,  s3 = s1 * c2 + c1 * s2;   // triple angle
        int i0 = padi(base), i1 = padi(base + L), i2 = padi(base + 2 * L), i3 = padi(base + 3 * L);
        float x0r = sre[i0], x0i = sim[i0];
        float x1r = sre[i1], x1i = sim[i1];
        float x2r = sre[i2], x2i = sim[i2];
        float x3r = sre[i3], x3i = sim[i3];
        float t1r = x1r * c1 + x1i * s1, t1i = x1i * c1 - x1r * s1;
        float t2r = x2r * c2 + x2i * s2, t2i = x2i * c2 - x2r * s2;
        float t3r = x3r * c3 + x3i * s3, t3i = x3i * c3 - x3r * s3;
        float ar = x0r + t2r, ai = x0i + t2i;
        float cr = x0r - t2r, ci = x0i - t2i;
        float br_ = t1r + t3r, bi_ = t1i + t3i;
        float dr_ = t1r - t3r, di_ = t1i - t3i;
        sre[i0] = ar + br_; sim[i0] = ai + bi_;
        sre[i2] = ar - br_; sim[i2] = ai - bi_;
        sre[i1] = cr + di_; sim[i1] = ci - dr_;   // -i*(d)
        sre[i3] = cr - di_; sim[i3] = ci + dr_;
        __syncthreads();
    }
    // untangle: X[k] = P - i*e^{-i pi k/1024}*G; X[1024-k] = conj pair
    size_t xb = ((size_t)b * 512 + e) * 1024;
    float m_a, m_b, m_c, m_d, m_e = 0.f;
    {
        int k = t;
        int km = (1024 - k) & 1023;
        float vkr = sre[padi(k)],  vki = sim[padi(k)];
        float vmr = sre[padi(km)], vmi = sim[padi(km)];
        float p2r = 0.5f * (vkr + vmr), p2i = 0.5f * (vki - vmi);
        float gr  = 0.5f * (vkr - vmr), gi  = 0.5f * (vki + vmi);
        float sn, c;
        __sincosf((float)k * TWOPI_2048, &sn, &c);
        float rr = gr * c + gi * sn, ri = gi * c - gr * sn;
        float x0r = p2r + ri, x0i = p2i - rr;
        float x1r = p2r - ri, x1i = -p2i - rr;
        h16x2 o0; o0.x = (h16)x0r; o0.y = (h16)x0i;
        Xf[xb + k] = o0;
        m_a = sqrtf(x0r * x0r + x0i * x0i);
        m_b = sqrtf(x1r * x1r + x1i * x1i);   // mag[1024-k]; for k=0 this is mag[1024]
        if (k != 0) { h16x2 o1; o1.x = (h16)x1r; o1.y = (h16)x1i; Xf[xb + 1024 - k] = o1; }
    }
    {
        int k = t + 256;                       // 256..511, never 0
        int km = 1024 - k;
        float vkr = sre[padi(k)],  vki = sim[padi(k)];
        float vmr = sre[padi(km)], vmi = sim[padi(km)];
        float p2r = 0.5f * (vkr + vmr), p2i = 0.5f * (vki - vmi);
        float gr  = 0.5f * (vkr - vmr), gi  = 0.5f * (vki + vmi);
        float sn, c;
        __sincosf((float)k * TWOPI_2048, &sn, &c);
        float rr = gr * c + gi * sn, ri = gi * c - gr * sn;
        float x0r = p2r + ri, x0i = p2i - rr;
        float x1r = p2r - ri, x1i = -p2i - rr;
        h16x2 o0; o0.x = (h16)x0r; o0.y = (h16)x0i;
        Xf[xb + k] = o0;
        h16x2 o1; o1.x = (h16)x1r; o1.y = (h16)x1i;
        Xf[xb + 1024 - k] = o1;
        m_c = sqrtf(x0r * x0r + x0i * x0i);
        m_d = sqrtf(x1r * x1r + x1i * x1i);
    }
    if (t == 0) {                              // k = 512: X = conj(V[512])
        float vr = sre[padi(512)], vi = sim[padi(512)];
        h16x2 o; o.x = (h16)vr; o.y = (h16)(-vi);
        Xf[xb + 512] = o;
        m_e = sqrtf(vr * vr + vi * vi);
    }
    float lmax = fmaxf(fmaxf(fmaxf(m_a, m_b), fmaxf(m_c, m_d)), m_e);
    #pragma unroll
    for (int off = 32; off; off >>= 1) lmax = fmaxf(lmax, __shfl_xor(lmax, off));
    if ((t & 63) == 0) red[t >> 6] = lmax;
    __syncthreads();
    float thr = 0.1f * fmaxf(fmaxf(red[0], red[1]), fmaxf(red[2], red[3]));
    int wa = (t == 0) ? 1 : 2;                 // bins 0 and 1024 count once; others mirror
    int c = wa * ((m_a > thr) ? 1 : 0) + wa * ((m_b > thr) ? 1 : 0)
          + 2 * ((m_c > thr) ? 1 : 0) + 2 * ((m_d > thr) ? 1 : 0)
          + 2 * ((m_e > thr) ? 1 : 0);
    #pragma unroll
    for (int off = 32; off; off >>= 1) c += __shfl_xor(c, off);
    if ((t & 63) == 0) redc[t >> 6] = c;
    __syncthreads();
    if (t == 0) cnt2[blockIdx.x] = redc[0] + redc[1] + redc[2] + redc[3];
}

// ---------------- masked inverse: Hermitian fold + 1024-pt inverse radix-4 DIT ----------------
// N[b] computed inline from cnt2 (all blocks agree). N<=1024 always.
__global__ __launch_bounds__(256) void ifft_kernel(
    const h16x2* __restrict__ Xf, const int* __restrict__ cnt2, h16* __restrict__ h3e)
{
    __shared__ float sre[1056], sim[1056];
    __shared__ int redc[4];
    int t = threadIdx.x;
    int b = blockIdx.x >> 9, e = blockIdx.x & 511;
    // ---- inline N[b] from per-block counts (L2-hot, deterministic) ----
    int cA = cnt2[b * 512 + t] + cnt2[b * 512 + 256 + t];
    #pragma unroll
    for (int off = 32; off; off >>= 1) cA += __shfl_xor(cA, off);
    if ((t & 63) == 0) redc[t >> 6] = cA;
    __syncthreads();
    int Nb;
    {
        int tot = redc[0] + redc[1] + redc[2] + redc[3];
        float cc = (float)tot * (1.0f / 1048576.0f);
        float ratio = 0.5f * (1.f - cc);
        ratio = fminf(fmaxf(ratio, 0.1f), 1.f);
        int n = (int)(ratio * 2048.f);
        Nb = n < 1 ? 1 : (n > 2048 ? 2048 : n);
    }
    size_t xb = ((size_t)b * 512 + e) * 1024;
    // load masked X (2 bins per lane, 8B), scaled: k=0 -> 1/2048 ; k>=1 -> 1/4096
    #pragma unroll
    for (int j = 0; j < 2; ++j) {
        int k0 = j * 512 + 2 * t;
        h16x4 v = *(const h16x4*)((const h16*)(Xf + xb + k0));
        bool kp0 = k0 < Nb, kp1 = (k0 + 1) < Nb;
        float sc0 = (k0 == 0) ? (1.0f / 2048.0f) : (1.0f / 4096.0f);
        int p0 = padi(k0), p1 = padi(k0 + 1);
        sre[p0] = kp0 ? (float)v.x * sc0 : 0.f;
        sim[p0] = kp0 ? (float)v.y * sc0 : 0.f;
        sre[p1] = kp1 ? (float)v.z * (1.0f / 4096.0f) : 0.f;
        sim[p1] = kp1 ? (float)v.w * (1.0f / 4096.0f) : 0.f;
    }
    __syncthreads();
    // u_hat pairs in registers
    float u0r, u0i, u0pr = 0.f, u0pi = 0.f, u1r, u1i, u1pr, u1pi, u2r = 0.f, u2i = 0.f;
    {
        int k = t;
        if (k == 0) {
            float wr = sre[padi(0)], wi = sim[padi(0)];
            u0r = wr - wi; u0i = wi + wr;      // W[1024]=0 branch
        } else {
            int km = 1024 - k;
            float akr = sre[padi(k)],  aki = sim[padi(k)];
            float bkr = sre[padi(km)], bki = sim[padi(km)];
            float pr = akr + bkr, pi = aki - bki;
            float gr = akr - bkr, gi = aki + bki;
            float sn, c;
            __sincosf((float)k * TWOPI_2048, &sn, &c);
            float qr = gr * c - gi * sn, qi = gi * c + gr * sn;   // e^{+i theta}
            u0r = pr - qi; u0i = pi + qr;
            u0pr = pr + qi; u0pi = qr - pi;
        }
    }
    {
        int k = t + 256;
        int km = 1024 - k;
        float akr = sre[padi(k)],  aki = sim[padi(k)];
        float bkr = sre[padi(km)], bki = sim[padi(km)];
        float pr = akr + bkr, pi = aki - bki;
        float gr = akr - bkr, gi = aki + bki;
        float sn, c;
        __sincosf((float)k * TWOPI_2048, &sn, &c);
        float qr = gr * c - gi * sn, qi = gi * c + gr * sn;
        u1r = pr - qi; u1i = pi + qr;
        u1pr = pr + qi; u1pi = qr - pi;
    }
    if (t == 0) {
        float ar = sre[padi(512)], ai = sim[padi(512)];
        u2r = 2.f * ar; u2i = -2.f * ai;       // u_hat[512] = 2*conj(W'512)
    }
    __syncthreads();
    // scatter u_hat to digit-reversed positions (in-place over sre/sim)
    {
        int d = padi(dr5(t)); sre[d] = u0r; sim[d] = u0i;
        if (t != 0) { int dp = padi(dr5(1024 - t)); sre[dp] = u0pr; sim[dp] = u0pi; }
        int d1 = padi(dr5(t + 256)); sre[d1] = u1r; sim[d1] = u1i;
        int dp1 = padi(dr5(768 - t)); sre[dp1] = u1pr; sim[dp1] = u1pi;
        if (t == 0) { int d2 = padi(dr5(512)); sre[d2] = u2r; sim[d2] = u2i; }
    }
    __syncthreads();
    // 5 inverse radix-4 DIT stages (e^+); one butterfly per thread
    #pragma unroll
    for (int s = 0; s < 5; ++s) {
        int L = 1 << (2 * s);
        int K = 512 >> (2 * s);
        int p = t & (L - 1);
        int base = (t >> (2 * s)) * 4 * L + p;
        float th = (float)(p * K) * TWOPI_2048;
        float s1, c1;
        __sincosf(th, &s1, &c1);
        float c2 = 1.f - 2.f * s1 * s1, s2 = 2.f * s1 * c1;      // double angle
        float c3 = c1 * c2 - s1 * s2,  s3 = s1 * c2 + c1 * s2;   // triple angle
        int i0 = padi(base), i1 = padi(base + L), i2 = padi(base + 2 * L), i3 = padi(base + 3 * L);
        float x0r = sre[i0], x0i = sim[i0];
        float x1r = sre[i1], x1i = sim[i1];
        float x2r = sre[i2], x2i = sim[i2];
        float x3r = sre[i3], x3i = sim[i3];
        float t1r = x1r * c1 - x1i * s1, t1i = x1i * c1 + x1r * s1;  // e^{+}
        float t2r = x2r * c2 - x2i * s2, t2i = x2i * c2 + x2r * s2;
        float t3r = x3r * c3 - x3i * s3, t3i = x3i * c3 + x3r * s3;
        float ar = x0r + t2r, ai = x0i + t2i;
        float cr = x0r - t2r, ci = x0i - t2i;
        float br_ = t1r + t3r, bi_ = t1i + t3i;
        float dr_ = t1r - t3r, di_ = t1i - t3i;
        sre[i0] = ar + br_; sim[i0] = ai + bi_;
        sre[i2] = ar - br_; sim[i2] = ai - bi_;
        sre[i1] = cr - di_; sim[i1] = ci + dr_;   // +i*(d)
        sre[i3] = cr + di_; sim[i3] = ci - dr_;
        __syncthreads();
    }
    h16x2* drow = (h16x2*)(h3e + ((size_t)b * 512 + e) * 2048);
    #pragma unroll
    for (int j = 0; j < 4; ++j) {
        int n = j * 256 + t;
        h16x2 o; o.x = (h16)sre[padi(n)]; o.y = (h16)sim[padi(n)];
        drow[n] = o;                           // y[2n], y[2n+1]
    }
}

// ---------------- transpose h3e [b][e][l] -> h3t [b][l][e] ----------------
__global__ __launch_bounds__(256) void trans_kernel(
    const h16* __restrict__ h3e, h16* __restrict__ h3t)
{
    __shared__ h16 tl[64][68];
    int t = threadIdx.x;
    int blk = blockIdx.x;
    int b = blk >> 8, r = blk & 255;           // 8 e-tiles x 32 l-tiles
    int e0 = (r >> 5) * 64, l0 = (r & 31) * 64;
    #pragma unroll
    for (int it = 0; it < 4; ++it) {
        int idx = it * 256 + t;
        int er = idx >> 4, lc = (idx & 15) * 4;
        h16x4 v = *(const h16x4*)(h3e + ((size_t)(b * 512 + e0 + er)) * 2048 + l0 + lc);
        tl[er][lc] = v.x; tl[er][lc + 1] = v.y; tl[er][lc + 2] = v.z; tl[er][lc + 3] = v.w;
    }
    __syncthreads();
    #pragma unroll
    for (int it = 0; it < 4; ++it) {
        int idx = it * 256 + t;
        int lr = idx >> 4, ec = (idx & 15) * 4;
        h16x4 v;
        v.x = tl[ec][lr]; v.y = tl[ec + 1][lr]; v.z = tl[ec + 2][lr]; v.w = tl[ec + 3][lr];
        *(h16x4*)(h3t + ((size_t)(b * 2048 + l0 + lr)) * 512 + e0 + ec) = v;
    }
}

// ---------------- launch ----------------
extern "C" void kernel_launch(void* const* d_in, const int* in_sizes, int n_in,
                              void* d_out, int out_size, void* d_ws, size_t ws_size,
                              hipStream_t stream)
{
    const int*   x    = (const int*)d_in[0];
    const float* Wtok = (const float*)d_in[1];
    const float* Wpos = (const float*)d_in[2];
    const float* Wc1  = (const float*)d_in[3];
    const float* bc1  = (const float*)d_in[4];
    const float* Wc2  = (const float*)d_in[5];
    const float* bc2  = (const float*)d_in[6];
    const float* Wp   = (const float*)d_in[7];
    const float* bp   = (const float*)d_in[8];
    float* out = (float*)d_out;

    char* ws = (char*)d_ws;
    if (ws_size < WS_NEED) {
        hipMemsetAsync(d_out, 0xFF, 4, stream);  // sentinel: ws too small
        return;
    }
    h16*   Wt1  = (h16*)(ws + OFF_WT1);
    h16*   Wt2  = (h16*)(ws + OFF_WT2);
    h16*   Wpb  = (h16*)(ws + OFF_WPB);
    int*   cnt2 = (int*)(ws + OFF_CNT2);
    h16*   h0p  = (h16*)(ws + OFF_H0P);
    h16*   h1p  = (h16*)(ws + OFF_H1P);
    h16*   h2t  = (h16*)(ws + OFF_H2T);
    h16x2* Xf   = (h16x2*)(ws + OFF_XF);
    h16*   h3e  = (h16*)(ws + OFF_H3E);
    h16*   h3t  = (h16*)(ws + OFF_H3T);

    const int GEMM_LDS = 3 * (128 * 64) * (int)sizeof(h16);  // 49152 (B only)

    prep_embed_kernel<<<4548, 256, 0, stream>>>(
        Wc1, Wc2, Wp, Wt1, Wt2, Wpb, x, Wtok, Wpos, h0p, h1p);
    gemm3_kernel<KCONV, true, false, h16><<<dim3(64, 4), 512, GEMM_LDS, stream>>>(
        h0p, 1024, Wt1, bc1, h1p, 1024, 512, nullptr);
    gemm3_kernel<KCONV, true, true, h16><<<dim3(64, 4), 512, GEMM_LDS, stream>>>(
        h1p, 1024, Wt2, bc2, h2t, 0, 0, nullptr);
    fft_fwd_kernel<<<4096, 256, 0, stream>>>(h2t, Xf, cnt2);
    ifft_kernel<<<4096, 256, 0, stream>>>(Xf, cnt2, h3e);
    trans_kernel<<<2048, 256, 0, stream>>>(h3e, h3t);
    gemm3_kernel<512, false, false, float><<<dim3(64, 4), 512, GEMM_LDS, stream>>>(
        h3t, 0, Wpb, bp, out, 0, 0, out + (size_t)BB * LL * EE);
}

// Round 15
// 131.276 us; speedup vs baseline: 1.5177x; 1.5177x over previous
//
#include <hip/hip_runtime.h>
#include <hip/hip_bf16.h>
#include <cstddef>

// Problem dims
#define BB 8
#define LL 2048
#define EE 512
#define KCONV 1536   // 3*E
#define LPAD 2050    // L + 2 pad rows

typedef _Float16 h16;
typedef _Float16 h16x2 __attribute__((ext_vector_type(2)));
typedef _Float16 h16x4 __attribute__((ext_vector_type(4)));
typedef _Float16 h16x8 __attribute__((ext_vector_type(8)));
typedef float    f32x4 __attribute__((ext_vector_type(4)));

// ---------------- workspace layout (bytes) ----------------
static const size_t OFF_WT1  = 0;         // [512][1536] h16
static const size_t OFF_WT2  = 1572864;   // [512][1536] h16
static const size_t OFF_WPB  = 3145728;   // [512][512]  h16
static const size_t OFF_CNT2 = 3670016;   // int[4096] per-block counts
static const size_t OFF_H0P  = 4194304;   // [8][2050][512] h16
static const size_t OFF_H1P  = 20987904;  // [8][2050][512] h16
static const size_t OFF_H2T  = 37781504;  // [8][512][2048] h16 (conv2 out, transposed)
static const size_t OFF_XF   = 4194304;   // [8][512][1024] h16x2 half-spectrum (reuses h0p, dead)
static const size_t OFF_H3E  = 54558720;  // [8][512][2048] h16
static const size_t OFF_H3T  = 20987904;  // [8][2048][512] h16 (reuses h1p, dead after conv2)
static const size_t WS_NEED  = 71335936;

__device__ __forceinline__ int padi(int i) { return i + (i >> 5); }
// base-4 digit reversal of a 10-bit index (involution)
__device__ __forceinline__ int dr5(int n) {
    return ((n & 3) << 8) | (((n >> 2) & 3) << 6) | (((n >> 4) & 3) << 4)
         | (((n >> 6) & 3) << 2) | ((n >> 8) & 3);
}
#define TWOPI_2048 0.0030679616f   // 2*pi/2048

// ---------------- prep+embed merged: blocks 0..447 weight transpose, rest embed ----------------
__global__ __launch_bounds__(256) void prep_embed_kernel(
    const float* __restrict__ Wc1, const float* __restrict__ Wc2,
    const float* __restrict__ Wp,
    h16* __restrict__ Wt1, h16* __restrict__ Wt2, h16* __restrict__ Wpb,
    const int* __restrict__ x, const float* __restrict__ Wtok,
    const float* __restrict__ Wpos, h16* __restrict__ h0p, h16* __restrict__ h1p)
{
    int blk = blockIdx.x, t = threadIdx.x;
    __shared__ float tl[64][65];
    if (blk < 384) {
        const float* src = (blk < 192) ? Wc1 : Wc2;
        h16* dst = (blk < 192) ? Wt1 : Wt2;
        int tile = blk % 192;                 // 8 o-tiles x 24 r-tiles
        int o0 = (tile / 24) * 64, r0 = (tile % 24) * 64;
        #pragma unroll
        for (int it = 0; it < 4; ++it) {
            int idx = it * 256 + t;           // 1024 x float4
            int rr = idx >> 4, oo4 = (idx & 15) * 4;
            f32x4 v = *(const f32x4*)(src + (size_t)(r0 + rr) * 512 + o0 + oo4);
            tl[rr][oo4] = v[0]; tl[rr][oo4 + 1] = v[1];
            tl[rr][oo4 + 2] = v[2]; tl[rr][oo4 + 3] = v[3];
        }
        __syncthreads();
        #pragma unroll
        for (int it = 0; it < 4; ++it) {
            int idx = it * 256 + t;           // 1024 x h16x4
            int oo = idx & 63, rr4 = (idx >> 6) * 4;
            h16x4 v;
            v.x = (h16)tl[rr4][oo]; v.y = (h16)tl[rr4 + 1][oo];
            v.z = (h16)tl[rr4 + 2][oo]; v.w = (h16)tl[rr4 + 3][oo];
            *(h16x4*)(dst + (size_t)(o0 + oo) * 1536 + r0 + rr4) = v;
        }
    } else if (blk < 448) {
        int base = (blk - 384) * 4096;
        #pragma unroll
        for (int i = 0; i < 4; ++i) {
            int idx = base + (i * 256 + t) * 4;
            f32x4 a = *(const f32x4*)(Wp + idx);
            h16x4 v; v.x = (h16)a[0]; v.y = (h16)a[1]; v.z = (h16)a[2]; v.w = (h16)a[3];
            *(h16x4*)(Wpb + idx) = v;         // Wp already [out][in] = Bt[n][k]
        }
    } else {
        int rowg = (blk - 448) * 4 + (t >> 6);   // 0..16399
        int b = rowg / LPAD, r = rowg % LPAD;
        int lane = t & 63;
        size_t o = (size_t)rowg * 512 + lane * 8;
        if (r == 0 || r == LPAD - 1) {
            h16x8 z;
            #pragma unroll
            for (int j = 0; j < 8; ++j) z[j] = (h16)0.f;
            *(h16x8*)(h0p + o) = z;
            *(h16x8*)(h1p + o) = z;           // zero conv1-output pads too
        } else {
            int l = r - 1;
            int tok = x[b * LL + l];
            const f32x4* wt = (const f32x4*)(Wtok + (size_t)tok * 512 + lane * 8);
            const f32x4* wp = (const f32x4*)(Wpos + (size_t)l * 512 + lane * 8);
            f32x4 a0 = wt[0], a1 = wt[1], p0 = wp[0], p1 = wp[1];
            h16x8 v;
            #pragma unroll
            for (int j = 0; j < 4; ++j) v[j] = (h16)(a0[j] + p0[j]);
            #pragma unroll
            for (int j = 0; j < 4; ++j) v[4 + j] = (h16)(a1[j] + p1[j]);
            *(h16x8*)(h0p + o) = v;
        }
    }
}

// ---------------- GEMM: depth-3 pipeline + T2 swizzle + T5 setprio (R13 proven) ----------
// BM=256 BN=128 BK=64, 8 waves. Counted vmcnt(6), one barrier per K-tile (T4).
// T2: linear LDS dest + inverse-swizzled global source + swizzled ds_read.
template<int KTOT, bool RELU, bool TRANSOUT, typename OT>
__global__ __launch_bounds__(512) void gemm3_kernel(
    const h16* __restrict__ A, int a_extra,
    const h16* __restrict__ Bt, const float* __restrict__ bias,
    OT* __restrict__ out, int out_extra, int out_off,
    float* __restrict__ tail)
{
    extern __shared__ __align__(16) h16 lds[];   // 3x(256x64) A + 3x(128x64) B
    const int NKT = KTOT / 64;

    int t = threadIdx.x;                      // 0..511
    int w = t >> 6, ln = t & 63;
    int mt = blockIdx.x, nt = blockIdx.y;     // mt 0..63, nt 0..3
    int b = mt >> 3;                          // 8 256-row tiles per batch
    const h16* Ab = A + (size_t)mt * (256 * 512) + (size_t)b * a_extra;
    const h16* Bb = Bt + (size_t)nt * 128 * KTOT;

    int srow = t >> 3;                        // 0..63 staging row
    int scol = (t & 7) * 8;                   // staging col (h16)
    int wr = (w >> 1) * 64, wc = (w & 1) * 64;
    int fr = ln & 15, fg = (ln >> 4) * 8;

    f32x4 acc[4][4];
    #pragma unroll
    for (int m = 0; m < 4; ++m)
        #pragma unroll
        for (int n = 0; n < 4; ++n) acc[m][n] = {0.f, 0.f, 0.f, 0.f};

#define STAGE3(KT, BUF)                                                          \
    {                                                                            \
        int k0_ = (KT) * 64;                                                     \
        h16* sa_ = lds + (BUF) * 16384;                                          \
        h16* sb_ = lds + 49152 + (BUF) * 8192;                                   \
        _Pragma("unroll")                                                        \
        for (int q = 0; q < 4; ++q) {                                            \
            int row_ = q * 64 + srow;                                            \
            int sc_ = scol ^ ((row_ & 7) << 3);                                  \
            __builtin_amdgcn_global_load_lds(                                    \
                (const __attribute__((address_space(1))) unsigned int*)(Ab + (size_t)row_ * 512 + k0_ + sc_), \
                (__attribute__((address_space(3))) unsigned int*)(sa_ + row_ * 64 + scol), \
                16, 0, 0);                                                       \
        }                                                                        \
        _Pragma("unroll")                                                        \
        for (int q = 0; q < 2; ++q) {                                            \
            int row_ = q * 64 + srow;                                            \
            int sc_ = scol ^ ((row_ & 7) << 3);                                  \
            __builtin_amdgcn_global_load_lds(                                    \
                (const __attribute__((address_space(1))) unsigned int*)(Bb + (size_t)row_ * KTOT + k0_ + sc_), \
                (__attribute__((address_space(3))) unsigned int*)(sb_ + row_ * 64 + scol), \
                16, 0, 0);                                                       \
        }                                                                        \
    }

    // prologue: fill buffers 0 and 1 (12 loads in flight per wave)
    STAGE3(0, 0);
    STAGE3(1, 1);
    asm volatile("s_waitcnt vmcnt(6)" ::: "memory");   // tile 0 resident
    __builtin_amdgcn_s_barrier();
    __builtin_amdgcn_sched_barrier(0);

    int c = 0;
    for (int kt = 0; kt < NKT; ++kt) {
        int c2 = c + 2; if (c2 >= 3) c2 -= 3;
        if (kt + 2 < NKT) STAGE3(kt + 2, c2);          // buffer freed at last barrier
        const h16* sa = lds + c * 16384;
        const h16* sb = lds + 49152 + c * 8192;
        #pragma unroll
        for (int kk = 0; kk < 64; kk += 32) {
            h16x8 af[4], bf[4];
            #pragma unroll
            for (int m = 0; m < 4; ++m) {
                int arow = wr + m * 16 + fr;
                af[m] = *(const h16x8*)(sa + arow * 64 + ((kk + fg) ^ ((arow & 7) << 3)));
            }
            #pragma unroll
            for (int n = 0; n < 4; ++n) {
                int brow = wc + n * 16 + fr;
                bf[n] = *(const h16x8*)(sb + brow * 64 + ((kk + fg) ^ ((brow & 7) << 3)));
            }
            __builtin_amdgcn_s_setprio(1);
            #pragma unroll
            for (int m = 0; m < 4; ++m)
                #pragma unroll
                for (int n = 0; n < 4; ++n)
                    acc[m][n] = __builtin_amdgcn_mfma_f32_16x16x32_f16(af[m], bf[n], acc[m][n], 0, 0, 0);
            __builtin_amdgcn_s_setprio(0);
        }
        if (kt + 1 < NKT) {
            if (kt + 2 < NKT) { asm volatile("s_waitcnt vmcnt(6)" ::: "memory"); }
            else              { asm volatile("s_waitcnt vmcnt(0)" ::: "memory"); }
            __builtin_amdgcn_s_barrier();
            __builtin_amdgcn_sched_barrier(0);
        }
        c = c + 1; if (c >= 3) c -= 3;
    }
#undef STAGE3

    int fq = (ln >> 4) * 4;
    if constexpr (TRANSOUT) {
        int mtl = (mt & 7) * 256;
        #pragma unroll
        for (int n = 0; n < 4; ++n) {
            int col = nt * 128 + wc + n * 16 + fr;
            float bv = bias[col];
            #pragma unroll
            for (int m = 0; m < 4; ++m) {
                h16x4 hv;
                #pragma unroll
                for (int r = 0; r < 4; ++r) {
                    float xv = acc[m][n][r] + bv;
                    if (RELU) xv = fmaxf(xv, 0.f);
                    hv[r] = (h16)xv;
                }
                int l0a = mtl + wr + m * 16 + fq;
                *(h16x4*)((h16*)out + ((size_t)(b * 512 + col)) * 2048 + l0a) = hv;
            }
        }
    } else {
        #pragma unroll
        for (int n = 0; n < 4; ++n) {
            int col = nt * 128 + wc + n * 16 + fr;
            float bv = bias[col];
            #pragma unroll
            for (int m = 0; m < 4; ++m) {
                #pragma unroll
                for (int r = 0; r < 4; ++r) {
                    int grow = wr + m * 16 + fq + r;
                    float v = acc[m][n][r] + bv;
                    if (RELU) v = fmaxf(v, 0.f);
                    size_t oi = (size_t)(mt * 256 + grow) * 512 + (size_t)b * out_extra + out_off + col;
                    out[oi] = (OT)v;
                }
            }
        }
    }
    if (tail && mt == 0 && nt == 0 && t == 0) tail[0] = 0.f;
}

// ---------------- forward: real 2048-FFT via 1024-pt radix-4 DIT + untangle ----------------
// Threshold test on SQUARED magnitudes (m^2 > 0.01*max^2 <=> m > 0.1*max).
__global__ __launch_bounds__(256) void fft_fwd_kernel(
    const h16* __restrict__ h2t, h16x2* __restrict__ Xf, int* __restrict__ cnt2)
{
    __shared__ float sre[1056], sim[1056];
    __shared__ float red[4]; __shared__ int redc[4];
    int t = threadIdx.x;
    int b = blockIdx.x >> 9, e = blockIdx.x & 511;
    const h16* src = h2t + ((size_t)b * 512 + e) * 2048;
    #pragma unroll
    for (int j = 0; j < 2; ++j) {
        int n0 = j * 512 + t * 2;
        h16x4 v = *(const h16x4*)(src + n0 * 2);
        int d0 = padi(dr5(n0)), d1 = padi(dr5(n0 + 1));
        sre[d0] = (float)v.x; sim[d0] = (float)v.y;
        sre[d1] = (float)v.z; sim[d1] = (float)v.w;
    }
    __syncthreads();
    #pragma unroll
    for (int s = 0; s < 5; ++s) {
        int L = 1 << (2 * s);
        int K = 512 >> (2 * s);
        int p = t & (L - 1);
        int base = (t >> (2 * s)) * 4 * L + p;   // one butterfly per thread
        float th = (float)(p * K) * TWOPI_2048;
        float s1, c1;
        __sincosf(th, &s1, &c1);
        float c2 = 1.f - 2.f * s1 * s1, s2 = 2.f * s1 * c1;      // double angle
        float c3 = c1 * c2 - s1 * s2,  s3 = s1 * c2 + c1 * s2;   // triple angle
        int i0 = padi(base), i1 = padi(base + L), i2 = padi(base + 2 * L), i3 = padi(base + 3 * L);
        float x0r = sre[i0], x0i = sim[i0];
        float x1r = sre[i1], x1i = sim[i1];
        float x2r = sre[i2], x2i = sim[i2];
        float x3r = sre[i3], x3i = sim[i3];
        float t1r = x1r * c1 + x1i * s1, t1i = x1i * c1 - x1r * s1;
        float t2r = x2r * c2 + x2i * s2, t2i = x2i * c2 - x2r * s2;
        float t3r = x3r * c3 + x3i * s3, t3i = x3i * c3 - x3r * s3;
        float ar = x0r + t2r, ai = x0i + t2i;
        float cr = x0r - t2r, ci = x0i - t2i;
        float br_ = t1r + t3r, bi_ = t1i + t3i;
        float dr_ = t1r - t3r, di_ = t1i - t3i;
        sre[i0] = ar + br_; sim[i0] = ai + bi_;
        sre[i2] = ar - br_; sim[i2] = ai - bi_;
        sre[i1] = cr + di_; sim[i1] = ci - dr_;   // -i*(d)
        sre[i3] = cr - di_; sim[i3] = ci + dr_;
        __syncthreads();
    }
    // untangle: X[k] = P - i*e^{-i pi k/1024}*G; X[1024-k] = conj pair
    size_t xb = ((size_t)b * 512 + e) * 1024;
    float m_a, m_b, m_c, m_d, m_e = 0.f;
    {
        int k = t;
        int km = (1024 - k) & 1023;
        float vkr = sre[padi(k)],  vki = sim[padi(k)];
        float vmr = sre[padi(km)], vmi = sim[padi(km)];
        float p2r = 0.5f * (vkr + vmr), p2i = 0.5f * (vki - vmi);
        float gr  = 0.5f * (vkr - vmr), gi  = 0.5f * (vki + vmi);
        float sn, c;
        __sincosf((float)k * TWOPI_2048, &sn, &c);
        float rr = gr * c + gi * sn, ri = gi * c - gr * sn;
        float x0r = p2r + ri, x0i = p2i - rr;
        float x1r = p2r - ri, x1i = -p2i - rr;
        h16x2 o0; o0.x = (h16)x0r; o0.y = (h16)x0i;
        Xf[xb + k] = o0;
        m_a = x0r * x0r + x0i * x0i;
        m_b = x1r * x1r + x1i * x1i;          // mag2[1024-k]; for k=0 this is mag2[1024]
        if (k != 0) { h16x2 o1; o1.x = (h16)x1r; o1.y = (h16)x1i; Xf[xb + 1024 - k] = o1; }
    }
    {
        int k = t + 256;                       // 256..511, never 0
        int km = 1024 - k;
        float vkr = sre[padi(k)],  vki = sim[padi(k)];
        float vmr = sre[padi(km)], vmi = sim[padi(km)];
        float p2r = 0.5f * (vkr + vmr), p2i = 0.5f * (vki - vmi);
        float gr  = 0.5f * (vkr - vmr), gi  = 0.5f * (vki + vmi);
        float sn, c;
        __sincosf((float)k * TWOPI_2048, &sn, &c);
        float rr = gr * c + gi * sn, ri = gi * c - gr * sn;
        float x0r = p2r + ri, x0i = p2i - rr;
        float x1r = p2r - ri, x1i = -p2i - rr;
        h16x2 o0; o0.x = (h16)x0r; o0.y = (h16)x0i;
        Xf[xb + k] = o0;
        h16x2 o1; o1.x = (h16)x1r; o1.y = (h16)x1i;
        Xf[xb + 1024 - k] = o1;
        m_c = x0r * x0r + x0i * x0i;
        m_d = x1r * x1r + x1i * x1i;
    }
    if (t == 0) {                              // k = 512: X = conj(V[512])
        float vr = sre[padi(512)], vi = sim[padi(512)];
        h16x2 o; o.x = (h16)vr; o.y = (h16)(-vi);
        Xf[xb + 512] = o;
        m_e = vr * vr + vi * vi;
    }
    float lmax = fmaxf(fmaxf(fmaxf(m_a, m_b), fmaxf(m_c, m_d)), m_e);
    #pragma unroll
    for (int off = 32; off; off >>= 1) lmax = fmaxf(lmax, __shfl_xor(lmax, off));
    if ((t & 63) == 0) red[t >> 6] = lmax;
    __syncthreads();
    float thr = 0.01f * fmaxf(fmaxf(red[0], red[1]), fmaxf(red[2], red[3]));
    int wa = (t == 0) ? 1 : 2;                 // bins 0 and 1024 count once; others mirror
    int c = wa * ((m_a > thr) ? 1 : 0) + wa * ((m_b > thr) ? 1 : 0)
          + 2 * ((m_c > thr) ? 1 : 0) + 2 * ((m_d > thr) ? 1 : 0)
          + 2 * ((m_e > thr) ? 1 : 0);
    #pragma unroll
    for (int off = 32; off; off >>= 1) c += __shfl_xor(c, off);
    if ((t & 63) == 0) redc[t >> 6] = c;
    __syncthreads();
    if (t == 0) cnt2[blockIdx.x] = redc[0] + redc[1] + redc[2] + redc[3];
}

// ---------------- masked inverse: Hermitian fold + 1024-pt inverse radix-4 DIT ----------------
// N[b] computed inline from cnt2 (all blocks agree). N<=1024 always.
__global__ __launch_bounds__(256) void ifft_kernel(
    const h16x2* __restrict__ Xf, const int* __restrict__ cnt2, h16* __restrict__ h3e)
{
    __shared__ float sre[1056], sim[1056];
    __shared__ int redc[4];
    int t = threadIdx.x;
    int b = blockIdx.x >> 9, e = blockIdx.x & 511;
    // ---- inline N[b] from per-block counts (L2-hot, deterministic) ----
    int cA = cnt2[b * 512 + t] + cnt2[b * 512 + 256 + t];
    #pragma unroll
    for (int off = 32; off; off >>= 1) cA += __shfl_xor(cA, off);
    if ((t & 63) == 0) redc[t >> 6] = cA;
    __syncthreads();
    int Nb;
    {
        int tot = redc[0] + redc[1] + redc[2] + redc[3];
        float cc = (float)tot * (1.0f / 1048576.0f);
        float ratio = 0.5f * (1.f - cc);
        ratio = fminf(fmaxf(ratio, 0.1f), 1.f);
        int n = (int)(ratio * 2048.f);
        Nb = n < 1 ? 1 : (n > 2048 ? 2048 : n);
    }
    size_t xb = ((size_t)b * 512 + e) * 1024;
    // load masked X (2 bins per lane, 8B), scaled: k=0 -> 1/2048 ; k>=1 -> 1/4096
    #pragma unroll
    for (int j = 0; j < 2; ++j) {
        int k0 = j * 512 + 2 * t;
        h16x4 v = *(const h16x4*)((const h16*)(Xf + xb + k0));
        bool kp0 = k0 < Nb, kp1 = (k0 + 1) < Nb;
        float sc0 = (k0 == 0) ? (1.0f / 2048.0f) : (1.0f / 4096.0f);
        int p0 = padi(k0), p1 = padi(k0 + 1);
        sre[p0] = kp0 ? (float)v.x * sc0 : 0.f;
        sim[p0] = kp0 ? (float)v.y * sc0 : 0.f;
        sre[p1] = kp1 ? (float)v.z * (1.0f / 4096.0f) : 0.f;
        sim[p1] = kp1 ? (float)v.w * (1.0f / 4096.0f) : 0.f;
    }
    __syncthreads();
    // u_hat pairs in registers
    float u0r, u0i, u0pr = 0.f, u0pi = 0.f, u1r, u1i, u1pr, u1pi, u2r = 0.f, u2i = 0.f;
    {
        int k = t;
        if (k == 0) {
            float wr = sre[padi(0)], wi = sim[padi(0)];
            u0r = wr - wi; u0i = wi + wr;      // W[1024]=0 branch
        } else {
            int km = 1024 - k;
            float akr = sre[padi(k)],  aki = sim[padi(k)];
            float bkr = sre[padi(km)], bki = sim[padi(km)];
            float pr = akr + bkr, pi = aki - bki;
            float gr = akr - bkr, gi = aki + bki;
            float sn, c;
            __sincosf((float)k * TWOPI_2048, &sn, &c);
            float qr = gr * c - gi * sn, qi = gi * c + gr * sn;   // e^{+i theta}
            u0r = pr - qi; u0i = pi + qr;
            u0pr = pr + qi; u0pi = qr - pi;
        }
    }
    {
        int k = t + 256;
        int km = 1024 - k;
        float akr = sre[padi(k)],  aki = sim[padi(k)];
        float bkr = sre[padi(km)], bki = sim[padi(km)];
        float pr = akr + bkr, pi = aki - bki;
        float gr = akr - bkr, gi = aki + bki;
        float sn, c;
        __sincosf((float)k * TWOPI_2048, &sn, &c);
        float qr = gr * c - gi * sn, qi = gi * c + gr * sn;
        u1r = pr - qi; u1i = pi + qr;
        u1pr = pr + qi; u1pi = qr - pi;
    }
    if (t == 0) {
        float ar = sre[padi(512)], ai = sim[padi(512)];
        u2r = 2.f * ar; u2i = -2.f * ai;       // u_hat[512] = 2*conj(W'512)
    }
    __syncthreads();
    // scatter u_hat to digit-reversed positions (in-place over sre/sim)
    {
        int d = padi(dr5(t)); sre[d] = u0r; sim[d] = u0i;
        if (t != 0) { int dp = padi(dr5(1024 - t)); sre[dp] = u0pr; sim[dp] = u0pi; }
        int d1 = padi(dr5(t + 256)); sre[d1] = u1r; sim[d1] = u1i;
        int dp1 = padi(dr5(768 - t)); sre[dp1] = u1pr; sim[dp1] = u1pi;
        if (t == 0) { int d2 = padi(dr5(512)); sre[d2] = u2r; sim[d2] = u2i; }
    }
    __syncthreads();
    // 5 inverse radix-4 DIT stages (e^+); one butterfly per thread
    #pragma unroll
    for (int s = 0; s < 5; ++s) {
        int L = 1 << (2 * s);
        int K = 512 >> (2 * s);
        int p = t & (L - 1);
        int base = (t >> (2 * s)) * 4 * L + p;
        float th = (float)(p * K) * TWOPI_2048;
        float s1, c1;
        __sincosf(th, &s1, &c1);
        float c2 = 1.f - 2.f * s1 * s1, s2 = 2.f * s1 * c1;      // double angle
        float c3 = c1 * c2 - s1 * s2,  s3 = s1 * c2 + c1 * s2;   // triple angle
        int i0 = padi(base), i1 = padi(base + L), i2 = padi(base + 2 * L), i3 = padi(base + 3 * L);
        float x0r = sre[i0], x0i = sim[i0];
        float x1r = sre[i1], x1i = sim[i1];
        float x2r = sre[i2], x2i = sim[i2];
        float x3r = sre[i3], x3i = sim[i3];
        float t1r = x1r * c1 - x1i * s1, t1i = x1i * c1 + x1r * s1;  // e^{+}
        float t2r = x2r * c2 - x2i * s2, t2i = x2i * c2 + x2r * s2;
        float t3r = x3r * c3 - x3i * s3, t3i = x3i * c3 + x3r * s3;
        float ar = x0r + t2r, ai = x0i + t2i;
        float cr = x0r - t2r, ci = x0i - t2i;
        float br_ = t1r + t3r, bi_ = t1i + t3i;
        float dr_ = t1r - t3r, di_ = t1i - t3i;
        sre[i0] = ar + br_; sim[i0] = ai + bi_;
        sre[i2] = ar - br_; sim[i2] = ai - bi_;
        sre[i1] = cr - di_; sim[i1] = ci + dr_;   // +i*(d)
        sre[i3] = cr + di_; sim[i3] = ci - dr_;
        __syncthreads();
    }
    h16x2* drow = (h16x2*)(h3e + ((size_t)b * 512 + e) * 2048);
    #pragma unroll
    for (int j = 0; j < 4; ++j) {
        int n = j * 256 + t;
        h16x2 o; o.x = (h16)sre[padi(n)]; o.y = (h16)sim[padi(n)];
        drow[n] = o;                           // y[2n], y[2n+1]
    }
}

// ---------------- transpose h3e [b][e][l] -> h3t [b][l][e] ----------------
__global__ __launch_bounds__(256) void trans_kernel(
    const h16* __restrict__ h3e, h16* __restrict__ h3t)
{
    __shared__ h16 tl[64][68];
    int t = threadIdx.x;
    int blk = blockIdx.x;
    int b = blk >> 8, r = blk & 255;           // 8 e-tiles x 32 l-tiles
    int e0 = (r >> 5) * 64, l0 = (r & 31) * 64;
    #pragma unroll
    for (int it = 0; it < 4; ++it) {
        int idx = it * 256 + t;
        int er = idx >> 4, lc = (idx & 15) * 4;
        h16x4 v = *(const h16x4*)(h3e + ((size_t)(b * 512 + e0 + er)) * 2048 + l0 + lc);
        tl[er][lc] = v.x; tl[er][lc + 1] = v.y; tl[er][lc + 2] = v.z; tl[er][lc + 3] = v.w;
    }
    __syncthreads();
    #pragma unroll
    for (int it = 0; it < 4; ++it) {
        int idx = it * 256 + t;
        int lr = idx >> 4, ec = (idx & 15) * 4;
        h16x4 v;
        v.x = tl[ec][lr]; v.y = tl[ec + 1][lr]; v.z = tl[ec + 2][lr]; v.w = tl[ec + 3][lr];
        *(h16x4*)(h3t + ((size_t)(b * 2048 + l0 + lr)) * 512 + e0 + ec) = v;
    }
}

// ---------------- launch ----------------
extern "C" void kernel_launch(void* const* d_in, const int* in_sizes, int n_in,
                              void* d_out, int out_size, void* d_ws, size_t ws_size,
                              hipStream_t stream)
{
    const int*   x    = (const int*)d_in[0];
    const float* Wtok = (const float*)d_in[1];
    const float* Wpos = (const float*)d_in[2];
    const float* Wc1  = (const float*)d_in[3];
    const float* bc1  = (const float*)d_in[4];
    const float* Wc2  = (const float*)d_in[5];
    const float* bc2  = (const float*)d_in[6];
    const float* Wp   = (const float*)d_in[7];
    const float* bp   = (const float*)d_in[8];
    float* out = (float*)d_out;

    char* ws = (char*)d_ws;
    if (ws_size < WS_NEED) {
        hipMemsetAsync(d_out, 0xFF, 4, stream);  // sentinel: ws too small
        return;
    }
    h16*   Wt1  = (h16*)(ws + OFF_WT1);
    h16*   Wt2  = (h16*)(ws + OFF_WT2);
    h16*   Wpb  = (h16*)(ws + OFF_WPB);
    int*   cnt2 = (int*)(ws + OFF_CNT2);
    h16*   h0p  = (h16*)(ws + OFF_H0P);
    h16*   h1p  = (h16*)(ws + OFF_H1P);
    h16*   h2t  = (h16*)(ws + OFF_H2T);
    h16x2* Xf   = (h16x2*)(ws + OFF_XF);
    h16*   h3e  = (h16*)(ws + OFF_H3E);
    h16*   h3t  = (h16*)(ws + OFF_H3T);

    const int GEMM_LDS = 3 * (256 * 64 + 128 * 64) * (int)sizeof(h16);  // 147456

    // raise dynamic-LDS cap (deterministic host-side call; capture-safe)
    hipFuncSetAttribute((const void*)&gemm3_kernel<KCONV, true, false, h16>,
                        hipFuncAttributeMaxDynamicSharedMemorySize, GEMM_LDS);
    hipFuncSetAttribute((const void*)&gemm3_kernel<KCONV, true, true, h16>,
                        hipFuncAttributeMaxDynamicSharedMemorySize, GEMM_LDS);
    hipFuncSetAttribute((const void*)&gemm3_kernel<512, false, false, float>,
                        hipFuncAttributeMaxDynamicSharedMemorySize, GEMM_LDS);

    prep_embed_kernel<<<4548, 256, 0, stream>>>(
        Wc1, Wc2, Wp, Wt1, Wt2, Wpb, x, Wtok, Wpos, h0p, h1p);
    gemm3_kernel<KCONV, true, false, h16><<<dim3(64, 4), 512, GEMM_LDS, stream>>>(
        h0p, 1024, Wt1, bc1, h1p, 1024, 512, nullptr);
    gemm3_kernel<KCONV, true, true, h16><<<dim3(64, 4), 512, GEMM_LDS, stream>>>(
        h1p, 1024, Wt2, bc2, h2t, 0, 0, nullptr);
    fft_fwd_kernel<<<4096, 256, 0, stream>>>(h2t, Xf, cnt2);
    ifft_kernel<<<4096, 256, 0, stream>>>(Xf, cnt2, h3e);
    trans_kernel<<<2048, 256, 0, stream>>>(h3e, h3t);
    gemm3_kernel<512, false, false, float><<<dim3(64, 4), 512, GEMM_LDS, stream>>>(
        h3t, 0, Wpb, bp, out, 0, 0, out + (size_t)BB * LL * EE);
}

// Round 16
// 131.020 us; speedup vs baseline: 1.5207x; 1.0020x over previous
//
#include <hip/hip_runtime.h>
#include <hip/hip_bf16.h>
#include <cstddef>

// Problem dims
#define BB 8
#define LL 2048
#define EE 512
#define KCONV 1536   // 3*E
#define LPAD 2050    // L + 2 pad rows

typedef _Float16 h16;
typedef _Float16 h16x2 __attribute__((ext_vector_type(2)));
typedef _Float16 h16x4 __attribute__((ext_vector_type(4)));
typedef _Float16 h16x8 __attribute__((ext_vector_type(8)));
typedef float    f32x4 __attribute__((ext_vector_type(4)));

// ---------------- workspace layout (bytes) ----------------
static const size_t OFF_WT1  = 0;         // [512][1536] h16
static const size_t OFF_WT2  = 1572864;   // [512][1536] h16
static const size_t OFF_WPB  = 3145728;   // [512][512]  h16
static const size_t OFF_CNT2 = 3670016;   // int[4096] per-block counts
static const size_t OFF_H0P  = 4194304;   // [8][2050][512] h16
static const size_t OFF_H1P  = 20987904;  // [8][2050][512] h16
static const size_t OFF_H2T  = 37781504;  // [8][512][2048] h16 (conv2 out, transposed)
static const size_t OFF_XF   = 4194304;   // [8][512][1024] h16x2 half-spectrum (reuses h0p, dead)
static const size_t OFF_H3E  = 54558720;  // [8][512][2048] h16
static const size_t OFF_H3T  = 20987904;  // [8][2048][512] h16 (reuses h1p, dead after conv2)
static const size_t WS_NEED  = 71335936;

__device__ __forceinline__ int padi(int i) { return i + (i >> 5); }
// base-4 digit reversal of a 10-bit index (involution)
__device__ __forceinline__ int dr5(int n) {
    return ((n & 3) << 8) | (((n >> 2) & 3) << 6) | (((n >> 4) & 3) << 4)
         | (((n >> 6) & 3) << 2) | ((n >> 8) & 3);
}
#define TWOPI_2048 0.0030679616f   // 2*pi/2048

// ---------------- prep+embed merged: blocks 0..447 weight transpose, rest embed ----------------
__global__ __launch_bounds__(256) void prep_embed_kernel(
    const float* __restrict__ Wc1, const float* __restrict__ Wc2,
    const float* __restrict__ Wp,
    h16* __restrict__ Wt1, h16* __restrict__ Wt2, h16* __restrict__ Wpb,
    const int* __restrict__ x, const float* __restrict__ Wtok,
    const float* __restrict__ Wpos, h16* __restrict__ h0p, h16* __restrict__ h1p)
{
    int blk = blockIdx.x, t = threadIdx.x;
    __shared__ float tl[64][65];
    if (blk < 384) {
        const float* src = (blk < 192) ? Wc1 : Wc2;
        h16* dst = (blk < 192) ? Wt1 : Wt2;
        int tile = blk % 192;                 // 8 o-tiles x 24 r-tiles
        int o0 = (tile / 24) * 64, r0 = (tile % 24) * 64;
        #pragma unroll
        for (int it = 0; it < 4; ++it) {
            int idx = it * 256 + t;           // 1024 x float4
            int rr = idx >> 4, oo4 = (idx & 15) * 4;
            f32x4 v = *(const f32x4*)(src + (size_t)(r0 + rr) * 512 + o0 + oo4);
            tl[rr][oo4] = v[0]; tl[rr][oo4 + 1] = v[1];
            tl[rr][oo4 + 2] = v[2]; tl[rr][oo4 + 3] = v[3];
        }
        __syncthreads();
        #pragma unroll
        for (int it = 0; it < 4; ++it) {
            int idx = it * 256 + t;           // 1024 x h16x4
            int oo = idx & 63, rr4 = (idx >> 6) * 4;
            h16x4 v;
            v.x = (h16)tl[rr4][oo]; v.y = (h16)tl[rr4 + 1][oo];
            v.z = (h16)tl[rr4 + 2][oo]; v.w = (h16)tl[rr4 + 3][oo];
            *(h16x4*)(dst + (size_t)(o0 + oo) * 1536 + r0 + rr4) = v;
        }
    } else if (blk < 448) {
        int base = (blk - 384) * 4096;
        #pragma unroll
        for (int i = 0; i < 4; ++i) {
            int idx = base + (i * 256 + t) * 4;
            f32x4 a = *(const f32x4*)(Wp + idx);
            h16x4 v; v.x = (h16)a[0]; v.y = (h16)a[1]; v.z = (h16)a[2]; v.w = (h16)a[3];
            *(h16x4*)(Wpb + idx) = v;         // Wp already [out][in] = Bt[n][k]
        }
    } else {
        int rowg = (blk - 448) * 4 + (t >> 6);   // 0..16399
        int b = rowg / LPAD, r = rowg % LPAD;
        int lane = t & 63;
        size_t o = (size_t)rowg * 512 + lane * 8;
        if (r == 0 || r == LPAD - 1) {
            h16x8 z;
            #pragma unroll
            for (int j = 0; j < 8; ++j) z[j] = (h16)0.f;
            *(h16x8*)(h0p + o) = z;
            *(h16x8*)(h1p + o) = z;           // zero conv1-output pads too
        } else {
            int l = r - 1;
            int tok = x[b * LL + l];
            const f32x4* wt = (const f32x4*)(Wtok + (size_t)tok * 512 + lane * 8);
            const f32x4* wp = (const f32x4*)(Wpos + (size_t)l * 512 + lane * 8);
            f32x4 a0 = wt[0], a1 = wt[1], p0 = wp[0], p1 = wp[1];
            h16x8 v;
            #pragma unroll
            for (int j = 0; j < 4; ++j) v[j] = (h16)(a0[j] + p0[j]);
            #pragma unroll
            for (int j = 0; j < 4; ++j) v[4 + j] = (h16)(a1[j] + p1[j]);
            *(h16x8*)(h0p + o) = v;
        }
    }
}

// ---------------- GEMM: depth-3 + T2 swizzle + cross-barrier fragment pipelining ----------
// BM=256 BN=128 BK=64, 8 waves. Counted vmcnt(6), one barrier per K-tile (T4).
// NEW: next tile's half0 fragment ds_reads are issued AFTER vmcnt (buffer
// resident) but BEFORE the barrier - their latency hides under the barrier
// wait, and post-barrier MFMAs start with operands in registers. half1 reads
// are issued at iter top, overlapping under half0's MFMAs. Buffer lifetime
// invariants identical to R13 (audited in round notes). NKT even always.
template<int KTOT, bool RELU, bool TRANSOUT, typename OT>
__global__ __launch_bounds__(512) void gemm3_kernel(
    const h16* __restrict__ A, int a_extra,
    const h16* __restrict__ Bt, const float* __restrict__ bias,
    OT* __restrict__ out, int out_extra, int out_off,
    float* __restrict__ tail)
{
    extern __shared__ __align__(16) h16 lds[];   // 3x(256x64) A + 3x(128x64) B
    const int NKT = KTOT / 64;                   // even (24 or 8)

    int t = threadIdx.x;                      // 0..511
    int w = t >> 6, ln = t & 63;
    int mt = blockIdx.x, nt = blockIdx.y;     // mt 0..63, nt 0..3
    int b = mt >> 3;                          // 8 256-row tiles per batch
    const h16* Ab = A + (size_t)mt * (256 * 512) + (size_t)b * a_extra;
    const h16* Bb = Bt + (size_t)nt * 128 * KTOT;

    int srow = t >> 3;                        // 0..63 staging row
    int scol = (t & 7) * 8;                   // staging col (h16)
    int wr = (w >> 1) * 64, wc = (w & 1) * 64;
    int fr = ln & 15, fg = (ln >> 4) * 8;

    f32x4 acc[4][4];
    #pragma unroll
    for (int m = 0; m < 4; ++m)
        #pragma unroll
        for (int n = 0; n < 4; ++n) acc[m][n] = {0.f, 0.f, 0.f, 0.f};

#define STAGE3(KT, BUF)                                                          \
    {                                                                            \
        int k0_ = (KT) * 64;                                                     \
        h16* sa_ = lds + (BUF) * 16384;                                          \
        h16* sb_ = lds + 49152 + (BUF) * 8192;                                   \
        _Pragma("unroll")                                                        \
        for (int q = 0; q < 4; ++q) {                                            \
            int row_ = q * 64 + srow;                                            \
            int sc_ = scol ^ ((row_ & 7) << 3);                                  \
            __builtin_amdgcn_global_load_lds(                                    \
                (const __attribute__((address_space(1))) unsigned int*)(Ab + (size_t)row_ * 512 + k0_ + sc_), \
                (__attribute__((address_space(3))) unsigned int*)(sa_ + row_ * 64 + scol), \
                16, 0, 0);                                                       \
        }                                                                        \
        _Pragma("unroll")                                                        \
        for (int q = 0; q < 2; ++q) {                                            \
            int row_ = q * 64 + srow;                                            \
            int sc_ = scol ^ ((row_ & 7) << 3);                                  \
            __builtin_amdgcn_global_load_lds(                                    \
                (const __attribute__((address_space(1))) unsigned int*)(Bb + (size_t)row_ * KTOT + k0_ + sc_), \
                (__attribute__((address_space(3))) unsigned int*)(sb_ + row_ * 64 + scol), \
                16, 0, 0);                                                       \
        }                                                                        \
    }

    // fragment read of one kk-half (H=0/1) from buffer BUF
#define RDFRAG_H(BUF, H, AF, BF)                                                 \
    {                                                                            \
        const h16* sa_ = lds + (BUF) * 16384;                                    \
        const h16* sb_ = lds + 49152 + (BUF) * 8192;                             \
        _Pragma("unroll")                                                        \
        for (int m = 0; m < 4; ++m) {                                            \
            int arow = wr + m * 16 + fr;                                         \
            AF[m] = *(const h16x8*)(sa_ + arow * 64 + (((H) * 32 + fg) ^ ((arow & 7) << 3))); \
        }                                                                        \
        _Pragma("unroll")                                                        \
        for (int n = 0; n < 4; ++n) {                                            \
            int brow = wc + n * 16 + fr;                                         \
            BF[n] = *(const h16x8*)(sb_ + brow * 64 + (((H) * 32 + fg) ^ ((brow & 7) << 3))); \
        }                                                                        \
    }

#define MFMA_H(AF, BF)                                                           \
    {                                                                            \
        __builtin_amdgcn_s_setprio(1);                                           \
        _Pragma("unroll")                                                        \
        for (int m = 0; m < 4; ++m)                                              \
            _Pragma("unroll")                                                    \
            for (int n = 0; n < 4; ++n)                                          \
                acc[m][n] = __builtin_amdgcn_mfma_f32_16x16x32_f16(AF[m], BF[n], acc[m][n], 0, 0, 0); \
        __builtin_amdgcn_s_setprio(0);                                           \
    }

    h16x8 afX[4], bfX[4], afY[4], bfY[4], af1[4], bf1[4];

    // prologue: stage 0,1; tile0 resident; preload tile0 half0
    STAGE3(0, 0);
    STAGE3(1, 1);
    asm volatile("s_waitcnt vmcnt(6)" ::: "memory");
    __builtin_amdgcn_s_barrier();
    __builtin_amdgcn_sched_barrier(0);
    RDFRAG_H(0, 0, afX, bfX);

    for (int kt = 0; kt < NKT; kt += 2) {
        int c0 = kt % 3, c1 = (kt + 1) % 3, cs2 = (kt + 2) % 3, cs3 = (kt + 3) % 3;
        // ---- even tile kt: frags half0 in afX/bfX ----
        if (kt + 2 < NKT) STAGE3(kt + 2, cs2);
        RDFRAG_H(c0, 1, af1, bf1);            // half1 reads overlap half0 MFMAs
        MFMA_H(afX, bfX);
        MFMA_H(af1, bf1);
        if (kt + 2 < NKT) { asm volatile("s_waitcnt vmcnt(6)" ::: "memory"); }
        else              { asm volatile("s_waitcnt vmcnt(0)" ::: "memory"); }
        RDFRAG_H(c1, 0, afY, bfY);            // next tile half0, hides under barrier
        __builtin_amdgcn_sched_barrier(0);
        __builtin_amdgcn_s_barrier();
        __builtin_amdgcn_sched_barrier(0);
        // ---- odd tile kt+1: frags half0 in afY/bfY ----
        if (kt + 3 < NKT) STAGE3(kt + 3, cs3);
        RDFRAG_H(c1, 1, af1, bf1);
        MFMA_H(afY, bfY);
        MFMA_H(af1, bf1);
        if (kt + 2 < NKT) {
            if (kt + 3 < NKT) { asm volatile("s_waitcnt vmcnt(6)" ::: "memory"); }
            else              { asm volatile("s_waitcnt vmcnt(0)" ::: "memory"); }
            RDFRAG_H(cs2, 0, afX, bfX);
            __builtin_amdgcn_sched_barrier(0);
            __builtin_amdgcn_s_barrier();
            __builtin_amdgcn_sched_barrier(0);
        }
    }
#undef STAGE3
#undef RDFRAG_H
#undef MFMA_H

    int fq = (ln >> 4) * 4;
    if constexpr (TRANSOUT) {
        int mtl = (mt & 7) * 256;
        #pragma unroll
        for (int n = 0; n < 4; ++n) {
            int col = nt * 128 + wc + n * 16 + fr;
            float bv = bias[col];
            #pragma unroll
            for (int m = 0; m < 4; ++m) {
                h16x4 hv;
                #pragma unroll
                for (int r = 0; r < 4; ++r) {
                    float xv = acc[m][n][r] + bv;
                    if (RELU) xv = fmaxf(xv, 0.f);
                    hv[r] = (h16)xv;
                }
                int l0a = mtl + wr + m * 16 + fq;
                *(h16x4*)((h16*)out + ((size_t)(b * 512 + col)) * 2048 + l0a) = hv;
            }
        }
    } else {
        #pragma unroll
        for (int n = 0; n < 4; ++n) {
            int col = nt * 128 + wc + n * 16 + fr;
            float bv = bias[col];
            #pragma unroll
            for (int m = 0; m < 4; ++m) {
                #pragma unroll
                for (int r = 0; r < 4; ++r) {
                    int grow = wr + m * 16 + fq + r;
                    float v = acc[m][n][r] + bv;
                    if (RELU) v = fmaxf(v, 0.f);
                    size_t oi = (size_t)(mt * 256 + grow) * 512 + (size_t)b * out_extra + out_off + col;
                    out[oi] = (OT)v;
                }
            }
        }
    }
    if (tail && mt == 0 && nt == 0 && t == 0) tail[0] = 0.f;
}

// ---------------- forward: real 2048-FFT via 1024-pt radix-4 DIT + untangle ----------------
// Threshold test on SQUARED magnitudes (m^2 > 0.01*max^2 <=> m > 0.1*max).
__global__ __launch_bounds__(256) void fft_fwd_kernel(
    const h16* __restrict__ h2t, h16x2* __restrict__ Xf, int* __restrict__ cnt2)
{
    __shared__ float sre[1056], sim[1056];
    __shared__ float red[4]; __shared__ int redc[4];
    int t = threadIdx.x;
    int b = blockIdx.x >> 9, e = blockIdx.x & 511;
    const h16* src = h2t + ((size_t)b * 512 + e) * 2048;
    #pragma unroll
    for (int j = 0; j < 2; ++j) {
        int n0 = j * 512 + t * 2;
        h16x4 v = *(const h16x4*)(src + n0 * 2);
        int d0 = padi(dr5(n0)), d1 = padi(dr5(n0 + 1));
        sre[d0] = (float)v.x; sim[d0] = (float)v.y;
        sre[d1] = (float)v.z; sim[d1] = (float)v.w;
    }
    __syncthreads();
    #pragma unroll
    for (int s = 0; s < 5; ++s) {
        int L = 1 << (2 * s);
        int K = 512 >> (2 * s);
        int p = t & (L - 1);
        int base = (t >> (2 * s)) * 4 * L + p;   // one butterfly per thread
        float th = (float)(p * K) * TWOPI_2048;
        float s1, c1;
        __sincosf(th, &s1, &c1);
        float c2 = 1.f - 2.f * s1 * s1, s2 = 2.f * s1 * c1;      // double angle
        float c3 = c1 * c2 - s1 * s2,  s3 = s1 * c2 + c1 * s2;   // triple angle
        int i0 = padi(base), i1 = padi(base + L), i2 = padi(base + 2 * L), i3 = padi(base + 3 * L);
        float x0r = sre[i0], x0i = sim[i0];
        float x1r = sre[i1], x1i = sim[i1];
        float x2r = sre[i2], x2i = sim[i2];
        float x3r = sre[i3], x3i = sim[i3];
        float t1r = x1r * c1 + x1i * s1, t1i = x1i * c1 - x1r * s1;
        float t2r = x2r * c2 + x2i * s2, t2i = x2i * c2 - x2r * s2;
        float t3r = x3r * c3 + x3i * s3, t3i = x3i * c3 - x3r * s3;
        float ar = x0r + t2r, ai = x0i + t2i;
        float cr = x0r - t2r, ci = x0i - t2i;
        float br_ = t1r + t3r, bi_ = t1i + t3i;
        float dr_ = t1r - t3r, di_ = t1i - t3i;
        sre[i0] = ar + br_; sim[i0] = ai + bi_;
        sre[i2] = ar - br_; sim[i2] = ai - bi_;
        sre[i1] = cr + di_; sim[i1] = ci - dr_;   // -i*(d)
        sre[i3] = cr - di_; sim[i3] = ci + dr_;
        __syncthreads();
    }
    // untangle: X[k] = P - i*e^{-i pi k/1024}*G; X[1024-k] = conj pair
    size_t xb = ((size_t)b * 512 + e) * 1024;
    float m_a, m_b, m_c, m_d, m_e = 0.f;
    {
        int k = t;
        int km = (1024 - k) & 1023;
        float vkr = sre[padi(k)],  vki = sim[padi(k)];
        float vmr = sre[padi(km)], vmi = sim[padi(km)];
        float p2r = 0.5f * (vkr + vmr), p2i = 0.5f * (vki - vmi);
        float gr  = 0.5f * (vkr - vmr), gi  = 0.5f * (vki + vmi);
        float sn, c;
        __sincosf((float)k * TWOPI_2048, &sn, &c);
        float rr = gr * c + gi * sn, ri = gi * c - gr * sn;
        float x0r = p2r + ri, x0i = p2i - rr;
        float x1r = p2r - ri, x1i = -p2i - rr;
        h16x2 o0; o0.x = (h16)x0r; o0.y = (h16)x0i;
        Xf[xb + k] = o0;
        m_a = x0r * x0r + x0i * x0i;
        m_b = x1r * x1r + x1i * x1i;          // mag2[1024-k]; for k=0 this is mag2[1024]
        if (k != 0) { h16x2 o1; o1.x = (h16)x1r; o1.y = (h16)x1i; Xf[xb + 1024 - k] = o1; }
    }
    {
        int k = t + 256;                       // 256..511, never 0
        int km = 1024 - k;
        float vkr = sre[padi(k)],  vki = sim[padi(k)];
        float vmr = sre[padi(km)], vmi = sim[padi(km)];
        float p2r = 0.5f * (vkr + vmr), p2i = 0.5f * (vki - vmi);
        float gr  = 0.5f * (vkr - vmr), gi  = 0.5f * (vki + vmi);
        float sn, c;
        __sincosf((float)k * TWOPI_2048, &sn, &c);
        float rr = gr * c + gi * sn, ri = gi * c - gr * sn;
        float x0r = p2r + ri, x0i = p2i - rr;
        float x1r = p2r - ri, x1i = -p2i - rr;
        h16x2 o0; o0.x = (h16)x0r; o0.y = (h16)x0i;
        Xf[xb + k] = o0;
        h16x2 o1; o1.x = (h16)x1r; o1.y = (h16)x1i;
        Xf[xb + 1024 - k] = o1;
        m_c = x0r * x0r + x0i * x0i;
        m_d = x1r * x1r + x1i * x1i;
    }
    if (t == 0) {                              // k = 512: X = conj(V[512])
        float vr = sre[padi(512)], vi = sim[padi(512)];
        h16x2 o; o.x = (h16)vr; o.y = (h16)(-vi);
        Xf[xb + 512] = o;
        m_e = vr * vr + vi * vi;
    }
    float lmax = fmaxf(fmaxf(fmaxf(m_a, m_b), fmaxf(m_c, m_d)), m_e);
    #pragma unroll
    for (int off = 32; off; off >>= 1) lmax = fmaxf(lmax, __shfl_xor(lmax, off));
    if ((t & 63) == 0) red[t >> 6] = lmax;
    __syncthreads();
    float thr = 0.01f * fmaxf(fmaxf(red[0], red[1]), fmaxf(red[2], red[3]));
    int wa = (t == 0) ? 1 : 2;                 // bins 0 and 1024 count once; others mirror
    int c = wa * ((m_a > thr) ? 1 : 0) + wa * ((m_b > thr) ? 1 : 0)
          + 2 * ((m_c > thr) ? 1 : 0) + 2 * ((m_d > thr) ? 1 : 0)
          + 2 * ((m_e > thr) ? 1 : 0);
    #pragma unroll
    for (int off = 32; off; off >>= 1) c += __shfl_xor(c, off);
    if ((t & 63) == 0) redc[t >> 6] = c;
    __syncthreads();
    if (t == 0) cnt2[blockIdx.x] = redc[0] + redc[1] + redc[2] + redc[3];
}

// ---------------- masked inverse: Hermitian fold + 1024-pt inverse radix-4 DIT ----------------
// N[b] computed inline from cnt2 (all blocks agree). N<=1024 always.
__global__ __launch_bounds__(256) void ifft_kernel(
    const h16x2* __restrict__ Xf, const int* __restrict__ cnt2, h16* __restrict__ h3e)
{
    __shared__ float sre[1056], sim[1056];
    __shared__ int redc[4];
    int t = threadIdx.x;
    int b = blockIdx.x >> 9, e = blockIdx.x & 511;
    // ---- inline N[b] from per-block counts (L2-hot, deterministic) ----
    int cA = cnt2[b * 512 + t] + cnt2[b * 512 + 256 + t];
    #pragma unroll
    for (int off = 32; off; off >>= 1) cA += __shfl_xor(cA, off);
    if ((t & 63) == 0) redc[t >> 6] = cA;
    __syncthreads();
    int Nb;
    {
        int tot = redc[0] + redc[1] + redc[2] + redc[3];
        float cc = (float)tot * (1.0f / 1048576.0f);
        float ratio = 0.5f * (1.f - cc);
        ratio = fminf(fmaxf(ratio, 0.1f), 1.f);
        int n = (int)(ratio * 2048.f);
        Nb = n < 1 ? 1 : (n > 2048 ? 2048 : n);
    }
    size_t xb = ((size_t)b * 512 + e) * 1024;
    // load masked X (2 bins per lane, 8B), scaled: k=0 -> 1/2048 ; k>=1 -> 1/4096
    #pragma unroll
    for (int j = 0; j < 2; ++j) {
        int k0 = j * 512 + 2 * t;
        h16x4 v = *(const h16x4*)((const h16*)(Xf + xb + k0));
        bool kp0 = k0 < Nb, kp1 = (k0 + 1) < Nb;
        float sc0 = (k0 == 0) ? (1.0f / 2048.0f) : (1.0f / 4096.0f);
        int p0 = padi(k0), p1 = padi(k0 + 1);
        sre[p0] = kp0 ? (float)v.x * sc0 : 0.f;
        sim[p0] = kp0 ? (float)v.y * sc0 : 0.f;
        sre[p1] = kp1 ? (float)v.z * (1.0f / 4096.0f) : 0.f;
        sim[p1] = kp1 ? (float)v.w * (1.0f / 4096.0f) : 0.f;
    }
    __syncthreads();
    // u_hat pairs in registers
    float u0r, u0i, u0pr = 0.f, u0pi = 0.f, u1r, u1i, u1pr, u1pi, u2r = 0.f, u2i = 0.f;
    {
        int k = t;
        if (k == 0) {
            float wr = sre[padi(0)], wi = sim[padi(0)];
            u0r = wr - wi; u0i = wi + wr;      // W[1024]=0 branch
        } else {
            int km = 1024 - k;
            float akr = sre[padi(k)],  aki = sim[padi(k)];
            float bkr = sre[padi(km)], bki = sim[padi(km)];
            float pr = akr + bkr, pi = aki - bki;
            float gr = akr - bkr, gi = aki + bki;
            float sn, c;
            __sincosf((float)k * TWOPI_2048, &sn, &c);
            float qr = gr * c - gi * sn, qi = gi * c + gr * sn;   // e^{+i theta}
            u0r = pr - qi; u0i = pi + qr;
            u0pr = pr + qi; u0pi = qr - pi;
        }
    }
    {
        int k = t + 256;
        int km = 1024 - k;
        float akr = sre[padi(k)],  aki = sim[padi(k)];
        float bkr = sre[padi(km)], bki = sim[padi(km)];
        float pr = akr + bkr, pi = aki - bki;
        float gr = akr - bkr, gi = aki + bki;
        float sn, c;
        __sincosf((float)k * TWOPI_2048, &sn, &c);
        float qr = gr * c - gi * sn, qi = gi * c + gr * sn;
        u1r = pr - qi; u1i = pi + qr;
        u1pr = pr + qi; u1pi = qr - pi;
    }
    if (t == 0) {
        float ar = sre[padi(512)], ai = sim[padi(512)];
        u2r = 2.f * ar; u2i = -2.f * ai;       // u_hat[512] = 2*conj(W'512)
    }
    __syncthreads();
    // scatter u_hat to digit-reversed positions (in-place over sre/sim)
    {
        int d = padi(dr5(t)); sre[d] = u0r; sim[d] = u0i;
        if (t != 0) { int dp = padi(dr5(1024 - t)); sre[dp] = u0pr; sim[dp] = u0pi; }
        int d1 = padi(dr5(t + 256)); sre[d1] = u1r; sim[d1] = u1i;
        int dp1 = padi(dr5(768 - t)); sre[dp1] = u1pr; sim[dp1] = u1pi;
        if (t == 0) { int d2 = padi(dr5(512)); sre[d2] = u2r; sim[d2] = u2i; }
    }
    __syncthreads();
    // 5 inverse radix-4 DIT stages (e^+); one butterfly per thread
    #pragma unroll
    for (int s = 0; s < 5; ++s) {
        int L = 1 << (2 * s);
        int K = 512 >> (2 * s);
        int p = t & (L - 1);
        int base = (t >> (2 * s)) * 4 * L + p;
        float th = (float)(p * K) * TWOPI_2048;
        float s1, c1;
        __sincosf(th, &s1, &c1);
        float c2 = 1.f - 2.f * s1 * s1, s2 = 2.f * s1 * c1;      // double angle
        float c3 = c1 * c2 - s1 * s2,  s3 = s1 * c2 + c1 * s2;   // triple angle
        int i0 = padi(base), i1 = padi(base + L), i2 = padi(base + 2 * L), i3 = padi(base + 3 * L);
        float x0r = sre[i0], x0i = sim[i0];
        float x1r = sre[i1], x1i = sim[i1];
        float x2r = sre[i2], x2i = sim[i2];
        float x3r = sre[i3], x3i = sim[i3];
        float t1r = x1r * c1 - x1i * s1, t1i = x1i * c1 + x1r * s1;  // e^{+}
        float t2r = x2r * c2 - x2i * s2, t2i = x2i * c2 + x2r * s2;
        float t3r = x3r * c3 - x3i * s3, t3i = x3i * c3 + x3r * s3;
        float ar = x0r + t2r, ai = x0i + t2i;
        float cr = x0r - t2r, ci = x0i - t2i;
        float br_ = t1r + t3r, bi_ = t1i + t3i;
        float dr_ = t1r - t3r, di_ = t1i - t3i;
        sre[i0] = ar + br_; sim[i0] = ai + bi_;
        sre[i2] = ar - br_; sim[i2] = ai - bi_;
        sre[i1] = cr - di_; sim[i1] = ci + dr_;   // +i*(d)
        sre[i3] = cr + di_; sim[i3] = ci - dr_;
        __syncthreads();
    }
    h16x2* drow = (h16x2*)(h3e + ((size_t)b * 512 + e) * 2048);
    #pragma unroll
    for (int j = 0; j < 4; ++j) {
        int n = j * 256 + t;
        h16x2 o; o.x = (h16)sre[padi(n)]; o.y = (h16)sim[padi(n)];
        drow[n] = o;                           // y[2n], y[2n+1]
    }
}

// ---------------- transpose h3e [b][e][l] -> h3t [b][l][e] ----------------
__global__ __launch_bounds__(256) void trans_kernel(
    const h16* __restrict__ h3e, h16* __restrict__ h3t)
{
    __shared__ h16 tl[64][68];
    int t = threadIdx.x;
    int blk = blockIdx.x;
    int b = blk >> 8, r = blk & 255;           // 8 e-tiles x 32 l-tiles
    int e0 = (r >> 5) * 64, l0 = (r & 31) * 64;
    #pragma unroll
    for (int it = 0; it < 4; ++it) {
        int idx = it * 256 + t;
        int er = idx >> 4, lc = (idx & 15) * 4;
        h16x4 v = *(const h16x4*)(h3e + ((size_t)(b * 512 + e0 + er)) * 2048 + l0 + lc);
        tl[er][lc] = v.x; tl[er][lc + 1] = v.y; tl[er][lc + 2] = v.z; tl[er][lc + 3] = v.w;
    }
    __syncthreads();
    #pragma unroll
    for (int it = 0; it < 4; ++it) {
        int idx = it * 256 + t;
        int lr = idx >> 4, ec = (idx & 15) * 4;
        h16x4 v;
        v.x = tl[ec][lr]; v.y = tl[ec + 1][lr]; v.z = tl[ec + 2][lr]; v.w = tl[ec + 3][lr];
        *(h16x4*)(h3t + ((size_t)(b * 2048 + l0 + lr)) * 512 + e0 + ec) = v;
    }
}

// ---------------- launch ----------------
extern "C" void kernel_launch(void* const* d_in, const int* in_sizes, int n_in,
                              void* d_out, int out_size, void* d_ws, size_t ws_size,
                              hipStream_t stream)
{
    const int*   x    = (const int*)d_in[0];
    const float* Wtok = (const float*)d_in[1];
    const float* Wpos = (const float*)d_in[2];
    const float* Wc1  = (const float*)d_in[3];
    const float* bc1  = (const float*)d_in[4];
    const float* Wc2  = (const float*)d_in[5];
    const float* bc2  = (const float*)d_in[6];
    const float* Wp   = (const float*)d_in[7];
    const float* bp   = (const float*)d_in[8];
    float* out = (float*)d_out;

    char* ws = (char*)d_ws;
    if (ws_size < WS_NEED) {
        hipMemsetAsync(d_out, 0xFF, 4, stream);  // sentinel: ws too small
        return;
    }
    h16*   Wt1  = (h16*)(ws + OFF_WT1);
    h16*   Wt2  = (h16*)(ws + OFF_WT2);
    h16*   Wpb  = (h16*)(ws + OFF_WPB);
    int*   cnt2 = (int*)(ws + OFF_CNT2);
    h16*   h0p  = (h16*)(ws + OFF_H0P);
    h16*   h1p  = (h16*)(ws + OFF_H1P);
    h16*   h2t  = (h16*)(ws + OFF_H2T);
    h16x2* Xf   = (h16x2*)(ws + OFF_XF);
    h16*   h3e  = (h16*)(ws + OFF_H3E);
    h16*   h3t  = (h16*)(ws + OFF_H3T);

    const int GEMM_LDS = 3 * (256 * 64 + 128 * 64) * (int)sizeof(h16);  // 147456

    // raise dynamic-LDS cap (deterministic host-side call; capture-safe)
    hipFuncSetAttribute((const void*)&gemm3_kernel<KCONV, true, false, h16>,
                        hipFuncAttributeMaxDynamicSharedMemorySize, GEMM_LDS);
    hipFuncSetAttribute((const void*)&gemm3_kernel<KCONV, true, true, h16>,
                        hipFuncAttributeMaxDynamicSharedMemorySize, GEMM_LDS);
    hipFuncSetAttribute((const void*)&gemm3_kernel<512, false, false, float>,
                        hipFuncAttributeMaxDynamicSharedMemorySize, GEMM_LDS);

    prep_embed_kernel<<<4548, 256, 0, stream>>>(
        Wc1, Wc2, Wp, Wt1, Wt2, Wpb, x, Wtok, Wpos, h0p, h1p);
    gemm3_kernel<KCONV, true, false, h16><<<dim3(64, 4), 512, GEMM_LDS, stream>>>(
        h0p, 1024, Wt1, bc1, h1p, 1024, 512, nullptr);
    gemm3_kernel<KCONV, true, true, h16><<<dim3(64, 4), 512, GEMM_LDS, stream>>>(
        h1p, 1024, Wt2, bc2, h2t, 0, 0, nullptr);
    fft_fwd_kernel<<<4096, 256, 0, stream>>>(h2t, Xf, cnt2);
    ifft_kernel<<<4096, 256, 0, stream>>>(Xf, cnt2, h3e);
    trans_kernel<<<2048, 256, 0, stream>>>(h3e, h3t);
    gemm3_kernel<512, false, false, float><<<dim3(64, 4), 512, GEMM_LDS, stream>>>(
        h3t, 0, Wpb, bp, out, 0, 0, out + (size_t)BB * LL * EE);
}